// Round 2
// baseline (3034.816 us; speedup 1.0000x reference)
//
#include <hip/hip_runtime.h>
#include <hip/hip_bf16.h>

// ---------------------------------------------------------------------------
// Swin block, fp32, chunked to keep workspace ~104 MB.
//   K0 ln-stats(x)        -> stats1 (mu,rstd per row of x)
//   per chunk c (4 chunks of 8 batch images / 512 windows / 25088 rows):
//     K2 qkv GEMM  A=LN1(x[perm]) fused        -> qc,kc,vc (chunk buf)
//     K3 fused window attention                 -> Oc       (chunk buf)
//     K4 proj GEMM + window-reverse + residual  -> d_out (residual stream x2)
//   K0 ln-stats(d_out)    -> stats2
//   per chunk c:
//     K6 fc1 GEMM (LN2 fused at A-load) + GELU  -> hidden (chunk buf)
//     K7 fc2 GEMM + residual                    -> d_out (final)
// ws floats: [0, SZ) chunk buffer (qc|kc|vc|Oc, later hidden) ;
//            [SZ, SZ+2*ROWS) stats1 ; [SZ+2*ROWS, SZ+4*ROWS) stats2
// ---------------------------------------------------------------------------

#define HW_ 56
#define NDIM 256
#define ROWS 100352          // 32 * 56 * 56
#define CHUNKS 4
#define CR 25088             // rows per chunk
#define CW 512               // windows per chunk
#define CQ 6422528           // CR*256 floats per q/k/v/O chunk
#define SCALE 0.17677669529663687f
#define LN_EPS 1e-5f
#define SHIFT 3

__device__ __forceinline__ void wave_reduce2(float& s, float& s2) {
#pragma unroll
  for (int off = 32; off; off >>= 1) {
    s += __shfl_xor(s, off);
    s2 += __shfl_xor(s2, off);
  }
}

// window-order row m -> row index into the (B, H*W) image layout
__device__ __forceinline__ int perm_row(int m) {
  int wi = m / 49, tok = m % 49;
  int bb = wi >> 6, wh = (wi >> 3) & 7, ww = wi & 7;
  int r = tok / 7, c2 = tok - r * 7;
  int sh = wh * 7 + r + SHIFT; if (sh >= HW_) sh -= HW_;
  int sw = ww * 7 + c2 + SHIFT; if (sw >= HW_) sw -= HW_;
  return bb * 3136 + sh * 56 + sw;
}

// ------------------------- K0: LN row stats --------------------------------
__global__ __launch_bounds__(256) void k_ln_stats(const float* __restrict__ src,
                                                  float* __restrict__ stats) {
  int row = (blockIdx.x << 2) + (threadIdx.x >> 6);
  int lane = threadIdx.x & 63;
  float4 v = reinterpret_cast<const float4*>(src + (size_t)row * NDIM)[lane];
  float s = v.x + v.y + v.z + v.w;
  float s2 = v.x * v.x + v.y * v.y + v.z * v.z + v.w * v.w;
  wave_reduce2(s, s2);
  if (lane == 0) {
    float mu = s * (1.0f / 256.0f);
    stats[row * 2] = mu;
    stats[row * 2 + 1] = rsqrtf(s2 * (1.0f / 256.0f) - mu * mu + LN_EPS);
  }
}

// ------------------------- GEMM (NT): C = A(MxK) * B(NxK)^T ----------------
#define BM 128
#define BN 64
#define BK 32
enum { E_QKV = 0, E_PROJ = 1, E_FC1 = 2, E_FC2 = 3 };

struct GP {
  const float* A; const float* B; const float* bias;
  float* out;
  const float* resid;
  const float* stats;                 // QKV: stats1 (x order); FC1: stats2
  const float* lnw; const float* lnb; // QKV: norm1; FC1: norm2
  float* q; float* k; float* v;       // QKV outputs (chunk-local)
  int K;
  int m_base;                          // global row offset of this chunk
};

template <int MODE>
__global__ __launch_bounds__(256, 2) void k_gemm(GP p) {
  __shared__ float As[BK][BM + 4];
  __shared__ float Bs[BK][BN + 4];
  const int tid = threadIdx.x;
  const int m0 = blockIdx.y * BM;       // chunk-local row base
  const int n0 = blockIdx.x * BN;
  const int tm = (tid >> 4) << 3;
  const int tn = (tid & 15) << 2;
  const int K = p.K;
  const int ar0 = tid >> 3;             // 0..31
  const int ac = (tid & 7) << 2;        // 0..28
  float acc[8][4] = {};

  for (int k0 = 0; k0 < K; k0 += BK) {
#pragma unroll
    for (int i = 0; i < 4; ++i) {
      int ar = ar0 + (i << 5);
      int mloc = m0 + ar;
      float4 f;
      if constexpr (MODE == E_QKV) {
        int xr = perm_row(p.m_base + mloc);
        f = *reinterpret_cast<const float4*>(p.A + (size_t)xr * 256 + k0 + ac);
        float mu = p.stats[xr * 2], rstd = p.stats[xr * 2 + 1];
        float4 lw = *reinterpret_cast<const float4*>(p.lnw + k0 + ac);
        float4 lb = *reinterpret_cast<const float4*>(p.lnb + k0 + ac);
        f.x = (f.x - mu) * rstd * lw.x + lb.x;
        f.y = (f.y - mu) * rstd * lw.y + lb.y;
        f.z = (f.z - mu) * rstd * lw.z + lb.z;
        f.w = (f.w - mu) * rstd * lw.w + lb.w;
      } else if constexpr (MODE == E_FC1) {
        int g = p.m_base + mloc;
        f = *reinterpret_cast<const float4*>(p.A + (size_t)g * 256 + k0 + ac);
        float mu = p.stats[g * 2], rstd = p.stats[g * 2 + 1];
        float4 lw = *reinterpret_cast<const float4*>(p.lnw + k0 + ac);
        float4 lb = *reinterpret_cast<const float4*>(p.lnb + k0 + ac);
        f.x = (f.x - mu) * rstd * lw.x + lb.x;
        f.y = (f.y - mu) * rstd * lw.y + lb.y;
        f.z = (f.z - mu) * rstd * lw.z + lb.z;
        f.w = (f.w - mu) * rstd * lw.w + lb.w;
      } else {
        f = *reinterpret_cast<const float4*>(p.A + (size_t)mloc * K + k0 + ac);
      }
      As[ac + 0][ar] = f.x; As[ac + 1][ar] = f.y;
      As[ac + 2][ar] = f.z; As[ac + 3][ar] = f.w;
    }
#pragma unroll
    for (int i = 0; i < 2; ++i) {
      int br = ar0 + (i << 5);
      float4 f = *reinterpret_cast<const float4*>(p.B + (size_t)(n0 + br) * K + k0 + ac);
      Bs[ac + 0][br] = f.x; Bs[ac + 1][br] = f.y;
      Bs[ac + 2][br] = f.z; Bs[ac + 3][br] = f.w;
    }
    __syncthreads();
#pragma unroll
    for (int kk = 0; kk < BK; ++kk) {
      float a[8], bb[4];
      *reinterpret_cast<float4*>(&a[0]) = *reinterpret_cast<float4*>(&As[kk][tm]);
      *reinterpret_cast<float4*>(&a[4]) = *reinterpret_cast<float4*>(&As[kk][tm + 4]);
      *reinterpret_cast<float4*>(&bb[0]) = *reinterpret_cast<float4*>(&Bs[kk][tn]);
#pragma unroll
      for (int i = 0; i < 8; ++i)
#pragma unroll
        for (int j = 0; j < 4; ++j) acc[i][j] = fmaf(a[i], bb[j], acc[i][j]);
    }
    __syncthreads();
  }

  float4 bias4 = *reinterpret_cast<const float4*>(p.bias + n0 + tn);
  const int n = n0 + tn;
#pragma unroll
  for (int i = 0; i < 8; ++i) {
    const int m = m0 + tm + i;            // chunk-local row
    if constexpr (MODE == E_QKV) {
      int wiL = m / 49, tok = m % 49;     // chunk-local window
      int which = n >> 8, head = (n >> 5) & 7, d = n & 31;
      float* dst = which == 0 ? p.q : (which == 1 ? p.k : p.v);
      float sc = which == 0 ? SCALE : 1.0f;
      float4 o;
      o.x = (acc[i][0] + bias4.x) * sc;
      o.y = (acc[i][1] + bias4.y) * sc;
      o.z = (acc[i][2] + bias4.z) * sc;
      o.w = (acc[i][3] + bias4.w) * sc;
      *reinterpret_cast<float4*>(dst + ((size_t)((wiL * 8 + head) * 49 + tok)) * 32 + d) = o;
    } else if constexpr (MODE == E_PROJ) {
      int g = p.m_base + m;
      size_t off = (size_t)perm_row(g) * NDIM + n;
      float4 rv = *reinterpret_cast<const float4*>(p.resid + off);
      float4 o;
      o.x = rv.x + acc[i][0] + bias4.x;
      o.y = rv.y + acc[i][1] + bias4.y;
      o.z = rv.z + acc[i][2] + bias4.z;
      o.w = rv.w + acc[i][3] + bias4.w;
      *reinterpret_cast<float4*>(p.out + off) = o;
    } else if constexpr (MODE == E_FC1) {
      float4 o;
      float t0 = acc[i][0] + bias4.x; o.x = 0.5f * t0 * (1.0f + erff(t0 * 0.70710678118f));
      float t1 = acc[i][1] + bias4.y; o.y = 0.5f * t1 * (1.0f + erff(t1 * 0.70710678118f));
      float t2 = acc[i][2] + bias4.z; o.z = 0.5f * t2 * (1.0f + erff(t2 * 0.70710678118f));
      float t3 = acc[i][3] + bias4.w; o.w = 0.5f * t3 * (1.0f + erff(t3 * 0.70710678118f));
      *reinterpret_cast<float4*>(p.out + (size_t)m * 1024 + n) = o;
    } else {  // E_FC2: A local, resid/out global
      size_t off = (size_t)(p.m_base + m) * NDIM + n;
      float4 rv = *reinterpret_cast<const float4*>(p.resid + off);
      float4 o;
      o.x = rv.x + acc[i][0] + bias4.x;
      o.y = rv.y + acc[i][1] + bias4.y;
      o.z = rv.z + acc[i][2] + bias4.z;
      o.w = rv.w + acc[i][3] + bias4.w;
      *reinterpret_cast<float4*>(p.out + off) = o;
    }
  }
}

// ------------------------- K3: fused window attention ----------------------
// one block (128 thr) per chunk-local (window, head)
__global__ __launch_bounds__(128) void k_attn(const float* __restrict__ qb,
                                              const float* __restrict__ kb,
                                              const float* __restrict__ vb,
                                              const float* __restrict__ rpb,
                                              float* __restrict__ O) {
  __shared__ float qs[49 * 36], ks[49 * 36], vs[49 * 36];
  __shared__ float S[49 * 49];
  const int tid = threadIdx.x;
  const int wh_ = blockIdx.x;           // local win*8 + head
  const int wl = wh_ >> 3, head = wh_ & 7;
  const size_t base = (size_t)wh_ * 49 * 32;

  for (int idx = tid; idx < 392; idx += 128) {
    int j = idx >> 3, c4 = (idx & 7) << 2;
    *reinterpret_cast<float4*>(&qs[j * 36 + c4]) = *reinterpret_cast<const float4*>(qb + base + j * 32 + c4);
    *reinterpret_cast<float4*>(&ks[j * 36 + c4]) = *reinterpret_cast<const float4*>(kb + base + j * 32 + c4);
    *reinterpret_cast<float4*>(&vs[j * 36 + c4]) = *reinterpret_cast<const float4*>(vb + base + j * 32 + c4);
  }
  __syncthreads();

  const int wwi = wl & 63;              // window index within one batch image
  const int wh = wwi >> 3, ww = wwi & 7;
  for (int e = tid; e < 2401; e += 128) {
    int i = e / 49, j = e - i * 49;
    float s = 0.f;
    const float4* qi = reinterpret_cast<const float4*>(&qs[i * 36]);
    const float4* kj = reinterpret_cast<const float4*>(&ks[j * 36]);
#pragma unroll
    for (int t = 0; t < 8; ++t) {
      float4 a = qi[t], b = kj[t];
      s += a.x * b.x + a.y * b.y + a.z * b.z + a.w * b.w;
    }
    int ri = i / 7, ci = i - ri * 7, rj = j / 7, cj = j - rj * 7;
    s += rpb[((ri - rj + 6) * 13 + (ci - cj + 6)) * 8 + head];
    int gih = wh * 7 + ri, giw = ww * 7 + ci;
    int gjh = wh * 7 + rj, gjw = ww * 7 + cj;
    int idi = (gih < 49 ? 0 : (gih < 53 ? 1 : 2)) * 3 + (giw < 49 ? 0 : (giw < 53 ? 1 : 2));
    int idj = (gjh < 49 ? 0 : (gjh < 53 ? 1 : 2)) * 3 + (gjw < 49 ? 0 : (gjw < 53 ? 1 : 2));
    S[e] = (idi != idj) ? s - 100.f : s;
  }
  __syncthreads();

  if (tid < 49) {
    float mx = -1e30f;
    for (int j = 0; j < 49; ++j) mx = fmaxf(mx, S[tid * 49 + j]);
    float sum = 0.f;
    for (int j = 0; j < 49; ++j) {
      float e = __expf(S[tid * 49 + j] - mx);
      S[tid * 49 + j] = e;
      sum += e;
    }
    float inv = 1.0f / sum;
    for (int j = 0; j < 49; ++j) S[tid * 49 + j] *= inv;
  }
  __syncthreads();

  float* Op = O + (size_t)wl * 49 * 256 + head * 32;
  for (int e = tid; e < 1568; e += 128) {
    int i = e >> 5, d = e & 31;
    float s = 0.f;
    for (int j = 0; j < 49; ++j) s = fmaf(S[i * 49 + j], vs[j * 36 + d], s);
    Op[(size_t)i * 256 + d] = s;
  }
}

// ---------------------------------------------------------------------------
extern "C" void kernel_launch(void* const* d_in, const int* in_sizes, int n_in,
                              void* d_out, int out_size, void* d_ws, size_t ws_size,
                              hipStream_t stream) {
  const float* x      = (const float*)d_in[0];
  const float* n1w    = (const float*)d_in[1];
  const float* n1b    = (const float*)d_in[2];
  const float* qkv_w  = (const float*)d_in[3];
  const float* qkv_b  = (const float*)d_in[4];
  const float* rpb    = (const float*)d_in[5];
  const float* proj_w = (const float*)d_in[6];
  const float* proj_b = (const float*)d_in[7];
  const float* n2w    = (const float*)d_in[8];
  const float* n2b    = (const float*)d_in[9];
  const float* fc1_w  = (const float*)d_in[10];
  const float* fc1_b  = (const float*)d_in[11];
  const float* fc2_w  = (const float*)d_in[12];
  const float* fc2_b  = (const float*)d_in[13];
  float* out = (float*)d_out;

  float* wsf = (float*)d_ws;
  const size_t SZ = (size_t)ROWS * NDIM;      // 25,690,112 floats
  float* qc     = wsf;                        // CQ floats
  float* kc     = wsf + CQ;
  float* vc     = wsf + 2 * (size_t)CQ;
  float* Oc     = wsf + 3 * (size_t)CQ;
  float* hidden = wsf;                        // CR*1024 = SZ floats (overlays)
  float* stats1 = wsf + SZ;                   // 2*ROWS
  float* stats2 = wsf + SZ + 2 * (size_t)ROWS;

  k_ln_stats<<<ROWS / 4, 256, 0, stream>>>(x, stats1);

  for (int c = 0; c < CHUNKS; ++c) {
    GP p1{}; p1.A = x; p1.B = qkv_w; p1.bias = qkv_b; p1.K = 256;
    p1.stats = stats1; p1.lnw = n1w; p1.lnb = n1b;
    p1.q = qc; p1.k = kc; p1.v = vc; p1.m_base = c * CR;
    k_gemm<E_QKV><<<dim3(768 / BN, CR / BM), 256, 0, stream>>>(p1);

    k_attn<<<CW * 8, 128, 0, stream>>>(qc, kc, vc, rpb, Oc);

    GP p2{}; p2.A = Oc; p2.B = proj_w; p2.bias = proj_b; p2.K = 256;
    p2.out = out; p2.resid = x; p2.m_base = c * CR;
    k_gemm<E_PROJ><<<dim3(256 / BN, CR / BM), 256, 0, stream>>>(p2);
  }

  k_ln_stats<<<ROWS / 4, 256, 0, stream>>>(out, stats2);

  for (int c = 0; c < CHUNKS; ++c) {
    GP p3{}; p3.A = out; p3.B = fc1_w; p3.bias = fc1_b; p3.K = 256;
    p3.out = hidden; p3.stats = stats2; p3.lnw = n2w; p3.lnb = n2b;
    p3.m_base = c * CR;
    k_gemm<E_FC1><<<dim3(1024 / BN, CR / BM), 256, 0, stream>>>(p3);

    GP p4{}; p4.A = hidden; p4.B = fc2_w; p4.bias = fc2_b; p4.K = 1024;
    p4.out = out; p4.resid = out; p4.m_base = c * CR;
    k_gemm<E_FC2><<<dim3(256 / BN, CR / BM), 256, 0, stream>>>(p4);
  }
}

// Round 3
// 1222.708 us; speedup vs baseline: 2.4820x; 2.4820x over previous
//
#include <hip/hip_runtime.h>
#include <hip/hip_bf16.h>

// ---------------------------------------------------------------------------
// Swin block: bf16-MFMA GEMMs + bf16 intermediates, fp32 residual stream.
//   K0 ln-stats(x)  -> stats1
//   per chunk (4 x 8 images / 512 windows / 25088 rows):
//     QKV GEMM  (A = LN1(x[perm]) fp32->bf16, MFMA)  -> qc,kc,vc (bf16)
//     attention (vector fp32, bf16 IO)               -> Oc (bf16)
//     PROJ GEMM (A = Oc bf16) + perm-scatter + resid -> d_out (fp32)
//   K0 ln-stats(d_out) -> stats2
//   per chunk:
//     FC1 GEMM (A = LN2(out) fused) + GELU -> hidden (bf16, overlays qkv)
//     FC2 GEMM (A = hidden) + resid        -> d_out
// ws: 4*CQE bf16 (51.4 MB) + stats (1.6 MB)
// ---------------------------------------------------------------------------

#define HW_ 56
#define ROWS 100352
#define CHUNKS 4
#define CR 25088
#define CQE 6422528          // CR*256 elements
#define SCALE 0.17677669529663687f
#define LN_EPS 1e-5f
#define SHIFT 3

typedef unsigned short u16;
typedef __attribute__((ext_vector_type(4))) float f32x4;
typedef __attribute__((ext_vector_type(8))) short bf16x8;
typedef __attribute__((ext_vector_type(8))) unsigned short ushort8_t;

__device__ __forceinline__ u16 f2bf(float f) {
  union { float f; unsigned u; } v; v.f = f;
  unsigned r = v.u + 0x7fffu + ((v.u >> 16) & 1u);
  return (u16)(r >> 16);
}
__device__ __forceinline__ float bf2f(u16 h) {
  union { unsigned u; float f; } v; v.u = ((unsigned)h) << 16;
  return v.f;
}

__device__ __forceinline__ void wave_reduce2(float& s, float& s2) {
#pragma unroll
  for (int off = 32; off; off >>= 1) {
    s += __shfl_xor(s, off);
    s2 += __shfl_xor(s2, off);
  }
}

// window-order row m -> row index into (B, H*W) image layout (with shift)
__device__ __forceinline__ int perm_row(int m) {
  int wi = m / 49, tok = m % 49;
  int bb = wi >> 6, wh = (wi >> 3) & 7, ww = wi & 7;
  int r = tok / 7, c2 = tok - r * 7;
  int sh = wh * 7 + r + SHIFT; if (sh >= HW_) sh -= HW_;
  int sw = ww * 7 + c2 + SHIFT; if (sw >= HW_) sw -= HW_;
  return bb * 3136 + sh * 56 + sw;
}

// ------------------------- K0: LN row stats --------------------------------
__global__ __launch_bounds__(256) void k_ln_stats(const float* __restrict__ src,
                                                  float* __restrict__ stats) {
  int row = (blockIdx.x << 2) + (threadIdx.x >> 6);
  int lane = threadIdx.x & 63;
  float4 v = reinterpret_cast<const float4*>(src + (size_t)row * 256)[lane];
  float s = v.x + v.y + v.z + v.w;
  float s2 = v.x * v.x + v.y * v.y + v.z * v.z + v.w * v.w;
  wave_reduce2(s, s2);
  if (lane == 0) {
    float mu = s * (1.0f / 256.0f);
    stats[row * 2] = mu;
    stats[row * 2 + 1] = rsqrtf(s2 * (1.0f / 256.0f) - mu * mu + LN_EPS);
  }
}

// ------------------------- MFMA GEMM (NT): C = A(MxK) * B(NxK)^T -----------
enum { E_QKV = 0, E_PROJ = 1, E_FC1 = 2, E_FC2 = 3 };

struct GP {
  const void* A; const float* B; const float* bias;
  float* out; u16* outb;
  const float* resid; const float* stats;
  const float* lnw; const float* lnb;
  u16* q; u16* k; u16* v;
  int K; int m_base;
};

// 128x128 tile, 4 waves (2x2), each wave 64x64 (4x4 frags of 16x16), BK=64.
// LDS tiles [dim][64] bf16, 16B-slot XOR swizzle: slot ^= (row & 7).
template <int MODE>
__global__ __launch_bounds__(256, 2) void k_gemm(GP p) {
  __shared__ short As[8192];
  __shared__ short Bs[8192];
  const int tid = threadIdx.x;
  const int lane = tid & 63;
  const int wv = tid >> 6;
  const int wm = (wv >> 1) << 6;
  const int wn = (wv & 1) << 6;
  const int m0 = blockIdx.y << 7;
  const int n0 = blockIdx.x << 7;
  const int K = p.K;
  f32x4 acc[4][4] = {};

  for (int k0 = 0; k0 < K; k0 += 64) {
    // ---- stage A ----
    if constexpr (MODE == E_PROJ || MODE == E_FC2) {
      const u16* Ab = (const u16*)p.A;
#pragma unroll
      for (int i = 0; i < 4; ++i) {
        int idx = (i << 8) + tid;
        int row = idx >> 3, k8 = (idx & 7) << 3;
        ushort8_t vv = *reinterpret_cast<const ushort8_t*>(
            Ab + (size_t)(m0 + row) * K + k0 + k8);
        *reinterpret_cast<ushort8_t*>(
            &As[(row << 6) + (((k8 >> 3) ^ (row & 7)) << 3)]) = vv;
      }
    } else {
      const float* Af = (const float*)p.A;
#pragma unroll
      for (int i = 0; i < 8; ++i) {
        int idx = (i << 8) + tid;
        int row = idx >> 4, k4 = (idx & 15) << 2;
        int grow;
        if constexpr (MODE == E_QKV) grow = perm_row(p.m_base + m0 + row);
        else                         grow = p.m_base + m0 + row;
        float4 f = *reinterpret_cast<const float4*>(Af + (size_t)grow * 256 + k0 + k4);
        float mu = p.stats[grow * 2], rstd = p.stats[grow * 2 + 1];
        float4 lw = *reinterpret_cast<const float4*>(p.lnw + k0 + k4);
        float4 lb = *reinterpret_cast<const float4*>(p.lnb + k0 + k4);
        f.x = (f.x - mu) * rstd * lw.x + lb.x;
        f.y = (f.y - mu) * rstd * lw.y + lb.y;
        f.z = (f.z - mu) * rstd * lw.z + lb.z;
        f.w = (f.w - mu) * rstd * lw.w + lb.w;
        short4 h = make_short4((short)f2bf(f.x), (short)f2bf(f.y),
                               (short)f2bf(f.z), (short)f2bf(f.w));
        *reinterpret_cast<short4*>(
            &As[(row << 6) + ((((k4 >> 3) ^ (row & 7)) << 3) | (k4 & 7))]) = h;
      }
    }
    // ---- stage B (fp32 weights) ----
#pragma unroll
    for (int i = 0; i < 8; ++i) {
      int idx = (i << 8) + tid;
      int row = idx >> 4, k4 = (idx & 15) << 2;
      float4 f = *reinterpret_cast<const float4*>(p.B + (size_t)(n0 + row) * K + k0 + k4);
      short4 h = make_short4((short)f2bf(f.x), (short)f2bf(f.y),
                             (short)f2bf(f.z), (short)f2bf(f.w));
      *reinterpret_cast<short4*>(
          &Bs[(row << 6) + ((((k4 >> 3) ^ (row & 7)) << 3) | (k4 & 7))]) = h;
    }
    __syncthreads();
    // ---- compute ----
#pragma unroll
    for (int kk = 0; kk < 64; kk += 32) {
      int slot = (kk >> 3) + (lane >> 4);
      bf16x8 a[4], b[4];
#pragma unroll
      for (int fm = 0; fm < 4; ++fm) {
        int r = wm + (fm << 4) + (lane & 15);
        a[fm] = *reinterpret_cast<const bf16x8*>(&As[(r << 6) + ((slot ^ (r & 7)) << 3)]);
      }
#pragma unroll
      for (int fn = 0; fn < 4; ++fn) {
        int r = wn + (fn << 4) + (lane & 15);
        b[fn] = *reinterpret_cast<const bf16x8*>(&Bs[(r << 6) + ((slot ^ (r & 7)) << 3)]);
      }
#pragma unroll
      for (int fm = 0; fm < 4; ++fm)
#pragma unroll
        for (int fn = 0; fn < 4; ++fn)
          acc[fm][fn] = __builtin_amdgcn_mfma_f32_16x16x32_bf16(a[fm], b[fn], acc[fm][fn], 0, 0, 0);
    }
    __syncthreads();
  }

  // ---- epilogue ----
  const int rb = (lane >> 4) << 2;
  const int cl = lane & 15;
  float barr[4];
#pragma unroll
  for (int fn = 0; fn < 4; ++fn) barr[fn] = p.bias[n0 + wn + (fn << 4) + cl];
#pragma unroll
  for (int fm = 0; fm < 4; ++fm) {
#pragma unroll
    for (int j = 0; j < 4; ++j) {
      const int m = m0 + wm + (fm << 4) + rb + j;   // chunk-local row
      int wiL = 0, tok = 0; size_t roff = 0;
      if constexpr (MODE == E_QKV) { wiL = m / 49; tok = m - wiL * 49; }
      if constexpr (MODE == E_PROJ) roff = (size_t)perm_row(p.m_base + m) * 256;
      if constexpr (MODE == E_FC2)  roff = (size_t)(p.m_base + m) * 256;
#pragma unroll
      for (int fn = 0; fn < 4; ++fn) {
        int col = n0 + wn + (fn << 4) + cl;
        float val = acc[fm][fn][j] + barr[fn];
        if constexpr (MODE == E_QKV) {
          int which = col >> 8, head = (col >> 5) & 7, d = col & 31;
          u16* dst = which == 0 ? p.q : (which == 1 ? p.k : p.v);
          if (which == 0) val *= SCALE;
          dst[((size_t)((wiL << 3) + head) * 49 + tok) * 32 + d] = f2bf(val);
        } else if constexpr (MODE == E_PROJ) {
          size_t off = roff + col;
          p.out[off] = p.resid[off] + val;
        } else if constexpr (MODE == E_FC1) {
          float g = 0.5f * val * (1.0f + erff(val * 0.70710678118f));
          p.outb[(size_t)m * 1024 + col] = f2bf(g);
        } else {
          size_t off = roff + col;
          p.out[off] = p.resid[off] + val;
        }
      }
    }
  }
}

// ------------------------- fused window attention (bf16 IO) ----------------
__global__ __launch_bounds__(128) void k_attn(const u16* __restrict__ qb,
                                              const u16* __restrict__ kb,
                                              const u16* __restrict__ vb,
                                              const float* __restrict__ rpb,
                                              u16* __restrict__ O) {
  __shared__ float qs[49 * 36], ks[49 * 36], vs[49 * 36];
  __shared__ float S[2401];
  const int tid = threadIdx.x;
  const int wh_ = blockIdx.x;           // local win*8 + head
  const int wl = wh_ >> 3, head = wh_ & 7;
  const size_t base = (size_t)wh_ * 1568;

  for (int idx = tid; idx < 196; idx += 128) {
    int j = idx >> 2, s = (idx & 3) << 3;
    ushort8_t a = *reinterpret_cast<const ushort8_t*>(qb + base + j * 32 + s);
    ushort8_t b = *reinterpret_cast<const ushort8_t*>(kb + base + j * 32 + s);
    ushort8_t c = *reinterpret_cast<const ushort8_t*>(vb + base + j * 32 + s);
#pragma unroll
    for (int t = 0; t < 8; ++t) {
      qs[j * 36 + s + t] = bf2f(a[t]);
      ks[j * 36 + s + t] = bf2f(b[t]);
      vs[j * 36 + s + t] = bf2f(c[t]);
    }
  }
  __syncthreads();

  const int wwi = wl & 63;
  const int wh = wwi >> 3, ww = wwi & 7;
  for (int e = tid; e < 2401; e += 128) {
    int i = e / 49, j = e - i * 49;
    float s = 0.f;
    const float4* qi = reinterpret_cast<const float4*>(&qs[i * 36]);
    const float4* kj = reinterpret_cast<const float4*>(&ks[j * 36]);
#pragma unroll
    for (int t = 0; t < 8; ++t) {
      float4 a = qi[t], b = kj[t];
      s += a.x * b.x + a.y * b.y + a.z * b.z + a.w * b.w;
    }
    int ri = i / 7, ci = i - ri * 7, rj = j / 7, cj = j - rj * 7;
    s += rpb[((ri - rj + 6) * 13 + (ci - cj + 6)) * 8 + head];
    int gih = wh * 7 + ri, giw = ww * 7 + ci;
    int gjh = wh * 7 + rj, gjw = ww * 7 + cj;
    int idi = (gih < 49 ? 0 : (gih < 53 ? 1 : 2)) * 3 + (giw < 49 ? 0 : (giw < 53 ? 1 : 2));
    int idj = (gjh < 49 ? 0 : (gjh < 53 ? 1 : 2)) * 3 + (gjw < 49 ? 0 : (gjw < 53 ? 1 : 2));
    S[e] = (idi != idj) ? s - 100.f : s;
  }
  __syncthreads();

  if (tid < 49) {
    float mx = -1e30f;
    for (int j = 0; j < 49; ++j) mx = fmaxf(mx, S[tid * 49 + j]);
    float sum = 0.f;
    for (int j = 0; j < 49; ++j) {
      float e = __expf(S[tid * 49 + j] - mx);
      S[tid * 49 + j] = e;
      sum += e;
    }
    float inv = 1.0f / sum;
    for (int j = 0; j < 49; ++j) S[tid * 49 + j] *= inv;
  }
  __syncthreads();

  u16* Op = O + (size_t)wl * 12544 + head * 32;
  for (int e = tid; e < 1568; e += 128) {
    int i = e >> 5, d = e & 31;
    float s = 0.f;
    for (int j = 0; j < 49; ++j) s = fmaf(S[i * 49 + j], vs[j * 36 + d], s);
    Op[(size_t)i * 256 + d] = f2bf(s);
  }
}

// ---------------------------------------------------------------------------
extern "C" void kernel_launch(void* const* d_in, const int* in_sizes, int n_in,
                              void* d_out, int out_size, void* d_ws, size_t ws_size,
                              hipStream_t stream) {
  const float* x      = (const float*)d_in[0];
  const float* n1w    = (const float*)d_in[1];
  const float* n1b    = (const float*)d_in[2];
  const float* qkv_w  = (const float*)d_in[3];
  const float* qkv_b  = (const float*)d_in[4];
  const float* rpb    = (const float*)d_in[5];
  const float* proj_w = (const float*)d_in[6];
  const float* proj_b = (const float*)d_in[7];
  const float* n2w    = (const float*)d_in[8];
  const float* n2b    = (const float*)d_in[9];
  const float* fc1_w  = (const float*)d_in[10];
  const float* fc1_b  = (const float*)d_in[11];
  const float* fc2_w  = (const float*)d_in[12];
  const float* fc2_b  = (const float*)d_in[13];
  float* out = (float*)d_out;

  u16* wsu = (u16*)d_ws;
  u16* qc = wsu;
  u16* kc = wsu + (size_t)CQE;
  u16* vc = wsu + 2 * (size_t)CQE;
  u16* Oc = wsu + 3 * (size_t)CQE;
  u16* hidden = wsu;                       // overlays qc..Oc (4*CQE = CR*1024)
  float* stats1 = (float*)(wsu + 4 * (size_t)CQE);
  float* stats2 = stats1 + 2 * (size_t)ROWS;

  k_ln_stats<<<ROWS / 4, 256, 0, stream>>>(x, stats1);

  for (int c = 0; c < CHUNKS; ++c) {
    GP p1{}; p1.A = x; p1.B = qkv_w; p1.bias = qkv_b; p1.K = 256;
    p1.stats = stats1; p1.lnw = n1w; p1.lnb = n1b;
    p1.q = qc; p1.k = kc; p1.v = vc; p1.m_base = c * CR;
    k_gemm<E_QKV><<<dim3(6, 196), 256, 0, stream>>>(p1);

    k_attn<<<4096, 128, 0, stream>>>(qc, kc, vc, rpb, Oc);

    GP p2{}; p2.A = Oc; p2.B = proj_w; p2.bias = proj_b; p2.K = 256;
    p2.out = out; p2.resid = x; p2.m_base = c * CR;
    k_gemm<E_PROJ><<<dim3(2, 196), 256, 0, stream>>>(p2);
  }

  k_ln_stats<<<ROWS / 4, 256, 0, stream>>>(out, stats2);

  for (int c = 0; c < CHUNKS; ++c) {
    GP p3{}; p3.A = out; p3.B = fc1_w; p3.bias = fc1_b; p3.K = 256;
    p3.outb = hidden; p3.stats = stats2; p3.lnw = n2w; p3.lnb = n2b;
    p3.m_base = c * CR;
    k_gemm<E_FC1><<<dim3(8, 196), 256, 0, stream>>>(p3);

    GP p4{}; p4.A = hidden; p4.B = fc2_w; p4.bias = fc2_b; p4.K = 1024;
    p4.out = out; p4.resid = out; p4.m_base = c * CR;
    k_gemm<E_FC2><<<dim3(2, 196), 256, 0, stream>>>(p4);
  }
}

// Round 11
// 812.080 us; speedup vs baseline: 3.7371x; 1.5056x over previous
//
#include <hip/hip_runtime.h>
#include <hip/hip_bf16.h>

// ---------------------------------------------------------------------------
// Swin block, all-bf16 MFMA pipeline, per-chunk LN buffer (~66 MB ws).
//   k_cvtw: weights fp32 -> bf16 (once)
//   k_bias: rpb + shift-mask -> bf16 table [4 cls][8 heads][49][64]
//   per chunk (4 x 512 windows / 25088 rows):
//     k_ln(perm, chunk): LN1(x) -> lnc bf16 (window order)
//     QKV GEMM (bf16 MFMA) -> qc,kc,vc [2048][49][32] bf16 (q pre-scaled)
//     k_attn: 1 wave per (window,head), MFMA QK^T/PV, in-reg softmax
//     PROJ GEMM + window-reverse + residual -> d_out (fp32)
//   per chunk:
//     k_ln(chunk): LN2(d_out) -> lnc bf16
//     FC1 GEMM + GELU -> hidden bf16 ; FC2 GEMM + resid -> d_out
// ws (u16): lnc [CQE] | qc kc vc Oc [4*CQE] (hidden overlays) | w bf16 | bias
// ---------------------------------------------------------------------------

#define HW_ 56
#define ROWS 100352
#define CHUNKS 4
#define CR 25088
#define CW 512
#define CQE 6422528          // CR*256
#define SCALE 0.17677669529663687f
#define LN_EPS 1e-5f
#define SHIFT 3

typedef unsigned short u16;
typedef unsigned int u32;
typedef __attribute__((ext_vector_type(4))) float f32x4;
typedef __attribute__((ext_vector_type(8))) short bf16x8;
typedef __attribute__((ext_vector_type(8))) unsigned short ushort8_t;

__device__ __forceinline__ u16 f2bf(float f) {
  union { float f; unsigned u; } v; v.f = f;
  unsigned r = v.u + 0x7fffu + ((v.u >> 16) & 1u);
  return (u16)(r >> 16);
}
__device__ __forceinline__ float bf2f(u16 h) {
  union { unsigned u; float f; } v; v.u = ((unsigned)h) << 16;
  return v.f;
}

__device__ __forceinline__ void wave_reduce2(float& s, float& s2) {
#pragma unroll
  for (int off = 32; off; off >>= 1) {
    s += __shfl_xor(s, off);
    s2 += __shfl_xor(s2, off);
  }
}

// window-order row m -> row index into (B, H*W) image layout (with shift)
__device__ __forceinline__ int perm_row(int m) {
  int wi = m / 49, tok = m % 49;
  int bb = wi >> 6, wh = (wi >> 3) & 7, ww = wi & 7;
  int r = tok / 7, c2 = tok - r * 7;
  int sh = wh * 7 + r + SHIFT; if (sh >= HW_) sh -= HW_;
  int sw = ww * 7 + c2 + SHIFT; if (sw >= HW_) sw -= HW_;
  return bb * 3136 + sh * 56 + sw;
}

// ------------------------- weight fp32->bf16 -------------------------------
__global__ __launch_bounds__(256) void k_cvtw(const float* __restrict__ qkv_w,
                                              const float* __restrict__ proj_w,
                                              const float* __restrict__ fc1_w,
                                              const float* __restrict__ fc2_w,
                                              u16* wq, u16* wp, u16* w1, u16* w2) {
  int bid = blockIdx.x;
  const float* s; u16* d; int off;
  if (bid < 192)      { s = qkv_w;  d = wq; off = bid * 1024; }
  else if (bid < 256) { s = proj_w; d = wp; off = (bid - 192) * 1024; }
  else if (bid < 512) { s = fc1_w;  d = w1; off = (bid - 256) * 1024; }
  else                { s = fc2_w;  d = w2; off = (bid - 512) * 1024; }
  int i = off + threadIdx.x * 4;
  float4 f = *reinterpret_cast<const float4*>(s + i);
  ushort4 h; h.x = f2bf(f.x); h.y = f2bf(f.y); h.z = f2bf(f.z); h.w = f2bf(f.w);
  *reinterpret_cast<ushort4*>(d + i) = h;
}

// ------------------------- bias table: rpb + mask --------------------------
// bias4[cls][head][q][k64] bf16 ; k>=49 -> -30000
// cls bit0: window in last row band (wh==7); bit1: last col band (ww==7).
__global__ __launch_bounds__(256) void k_bias(const float* __restrict__ rpb,
                                              u16* __restrict__ bias4) {
  int ch = blockIdx.x;               // cls*8 + head
  int cls = ch >> 3, head = ch & 7;
  for (int e = threadIdx.x; e < 3136; e += 256) {
    int q = e >> 6, k = e & 63;
    float v;
    if (k >= 49) {
      v = -30000.f;
    } else {
      int qr = (q * 9363) >> 16, qc = q - qr * 7;
      int kr = (k * 9363) >> 16, kc = k - kr * 7;
      v = rpb[((qr - kr + 6) * 13 + (qc - kc + 6)) * 8 + head];
      bool rd = (qr < 4) != (kr < 4);
      bool cd = (qc < 4) != (kc < 4);
      if (((cls & 1) && rd) || ((cls & 2) && cd)) v -= 100.f;
    }
    bias4[(size_t)ch * 3136 + e] = f2bf(v);
  }
}

// ------------------------- LN -> bf16 chunk (optionally permuted) ----------
__global__ __launch_bounds__(256) void k_ln(const float* __restrict__ src,
                                            u16* __restrict__ dst,
                                            const float* __restrict__ w,
                                            const float* __restrict__ b,
                                            int permuted, int m_base) {
  int rloc = (blockIdx.x << 2) + (threadIdx.x >> 6);
  int lane = threadIdx.x & 63;
  int g = m_base + rloc;
  int srow = permuted ? perm_row(g) : g;
  float4 v = reinterpret_cast<const float4*>(src + (size_t)srow * 256)[lane];
  float s = v.x + v.y + v.z + v.w;
  float s2 = v.x * v.x + v.y * v.y + v.z * v.z + v.w * v.w;
  wave_reduce2(s, s2);
  float mu = s * (1.0f / 256.0f);
  float rstd = rsqrtf(s2 * (1.0f / 256.0f) - mu * mu + LN_EPS);
  float4 wv = reinterpret_cast<const float4*>(w)[lane];
  float4 bv = reinterpret_cast<const float4*>(b)[lane];
  ushort4 h;
  h.x = f2bf((v.x - mu) * rstd * wv.x + bv.x);
  h.y = f2bf((v.y - mu) * rstd * wv.y + bv.y);
  h.z = f2bf((v.z - mu) * rstd * wv.z + bv.z);
  h.w = f2bf((v.w - mu) * rstd * wv.w + bv.w);
  *reinterpret_cast<ushort4*>(dst + (size_t)rloc * 256 + lane * 4) = h;
}

// ------------------------- MFMA GEMM (NT): C = A(MxK) * B(NxK)^T -----------
enum { E_QKV = 0, E_PROJ = 1, E_FC1 = 2, E_FC2 = 3 };

struct GP {
  const u16* A; const u16* B; const float* bias;
  float* out; u16* outb;
  const float* resid;
  u16* q; u16* k; u16* v;
  int K; int m_base;
};

// 128x128 tile, 4 waves (2x2), each 64x64 (4x4 frags of 16x16x32), BK=64.
// LDS [row][64] bf16, 16B-slot XOR swizzle: slot ^= (row & 7).
template <int MODE>
__global__ __launch_bounds__(256, 2) void k_gemm(GP p) {
  __shared__ __align__(16) u16 As[8192];
  __shared__ __align__(16) u16 Bs[8192];
  const int tid = threadIdx.x;
  const int lane = tid & 63;
  const int wv = tid >> 6;
  const int wm = (wv >> 1) << 6;
  const int wn = (wv & 1) << 6;
  const int m0 = blockIdx.y << 7;
  const int n0 = blockIdx.x << 7;
  const int K = p.K;
  f32x4 acc[4][4] = {};

  for (int k0 = 0; k0 < K; k0 += 64) {
#pragma unroll
    for (int i = 0; i < 4; ++i) {
      int slot = (i << 8) + tid;          // 0..1023
      int row = slot >> 3, k8 = (slot & 7) << 3;
      int loff = (row << 6) + (((k8 >> 3) ^ (row & 7)) << 3);
      ushort8_t va = *reinterpret_cast<const ushort8_t*>(p.A + (size_t)(m0 + row) * K + k0 + k8);
      *reinterpret_cast<ushort8_t*>(&As[loff]) = va;
      ushort8_t vb = *reinterpret_cast<const ushort8_t*>(p.B + (size_t)(n0 + row) * K + k0 + k8);
      *reinterpret_cast<ushort8_t*>(&Bs[loff]) = vb;
    }
    __syncthreads();
#pragma unroll
    for (int kk = 0; kk < 64; kk += 32) {
      int slot = (kk >> 3) + (lane >> 4);
      bf16x8 a[4], b[4];
#pragma unroll
      for (int fm = 0; fm < 4; ++fm) {
        int r = wm + (fm << 4) + (lane & 15);
        a[fm] = *reinterpret_cast<const bf16x8*>(&As[(r << 6) + ((slot ^ (r & 7)) << 3)]);
      }
#pragma unroll
      for (int fn = 0; fn < 4; ++fn) {
        int r = wn + (fn << 4) + (lane & 15);
        b[fn] = *reinterpret_cast<const bf16x8*>(&Bs[(r << 6) + ((slot ^ (r & 7)) << 3)]);
      }
#pragma unroll
      for (int fm = 0; fm < 4; ++fm)
#pragma unroll
        for (int fn = 0; fn < 4; ++fn)
          acc[fm][fn] = __builtin_amdgcn_mfma_f32_16x16x32_bf16(a[fm], b[fn], acc[fm][fn], 0, 0, 0);
    }
    __syncthreads();
  }

  // ---- epilogue ----
  const int rb = (lane >> 4) << 2;
  const int cl = lane & 15;
  float barr[4];
#pragma unroll
  for (int fn = 0; fn < 4; ++fn) barr[fn] = p.bias[n0 + wn + (fn << 4) + cl];
#pragma unroll
  for (int fm = 0; fm < 4; ++fm) {
#pragma unroll
    for (int j = 0; j < 4; ++j) {
      const int m = m0 + wm + (fm << 4) + rb + j;   // chunk-local row
      int wiL = 0, tok = 0; size_t roff = 0;
      if constexpr (MODE == E_QKV) { wiL = m / 49; tok = m - wiL * 49; }
      if constexpr (MODE == E_PROJ) roff = (size_t)perm_row(p.m_base + m) * 256;
      if constexpr (MODE == E_FC2)  roff = (size_t)(p.m_base + m) * 256;
#pragma unroll
      for (int fn = 0; fn < 4; ++fn) {
        int col = n0 + wn + (fn << 4) + cl;
        float val = acc[fm][fn][j] + barr[fn];
        if constexpr (MODE == E_QKV) {
          int which = col >> 8, head = (col >> 5) & 7, d = col & 31;
          u16* dst = which == 0 ? p.q : (which == 1 ? p.k : p.v);
          if (which == 0) val *= SCALE;
          dst[((size_t)((wiL << 3) + head) * 49 + tok) * 32 + d] = f2bf(val);
        } else if constexpr (MODE == E_PROJ) {
          size_t off = roff + col;
          p.out[off] = p.resid[off] + val;
        } else if constexpr (MODE == E_FC1) {
          float g = 0.5f * val * (1.0f + erff(val * 0.70710678118f));
          p.outb[(size_t)m * 1024 + col] = f2bf(g);
        } else {
          size_t off = roff + col;
          p.out[off] = p.resid[off] + val;
        }
      }
    }
  }
}

// ------------------------- MFMA window attention ---------------------------
// 4 waves/block, 1 wave = 1 (window, head). No __syncthreads (private LDS).
__global__ __launch_bounds__(256) void k_attn(const u16* __restrict__ qb,
                                              const u16* __restrict__ kb,
                                              const u16* __restrict__ vb,
                                              const u16* __restrict__ bias4,
                                              u16* __restrict__ O) {
  __shared__ __align__(16) u16 P_all[4][4096];    // [q][k] swizzled
  __shared__ __align__(16) u16 VT_all[4][2048];   // [d][k] swizzled
  __shared__ __align__(16) float sum_all[4][64];
  const int wv = threadIdx.x >> 6;
  const int lane = threadIdx.x & 63;
  const int rlane = lane & 15, glane = lane >> 4;
  u16* P = P_all[wv];
  u16* VT = VT_all[wv];
  float* sums = sum_all[wv];

  const int gw = blockIdx.x * 4 + wv;      // chunk-local window*8 + head
  const int wl = gw >> 3, head = gw & 7;
  const size_t base = (size_t)gw * 1568;   // 49*32
  const int wwi = wl & 63;
  const int cls = ((wwi >> 3) == 7 ? 1 : 0) | ((wwi & 7) == 7 ? 2 : 0);
  const u16* bias = bias4 + (size_t)((cls << 3) + head) * 3136;

  // ---- stage V^T into LDS (zero-fill k>=49) ----
#pragma unroll
  for (int i = 0; i < 16; ++i) ((u32*)VT)[lane + (i << 6)] = 0;
  if (lane < 49) {
    const u16* vr = vb + base + lane * 32;
    ushort8_t vv[4];
#pragma unroll
    for (int c = 0; c < 4; ++c) vv[c] = *reinterpret_cast<const ushort8_t*>(vr + (c << 3));
#pragma unroll
    for (int c = 0; c < 4; ++c)
#pragma unroll
      for (int t = 0; t < 8; ++t) {
        int d = (c << 3) + t;
        VT[(d << 6) + (lane ^ ((d & 7) << 3))] = vv[c][t];
      }
  }

  // ---- QK^T: S^T[k][q] = K · Q^T ----
  bf16x8 kf[4], qf[4];
#pragma unroll
  for (int t = 0; t < 4; ++t) {
    kf[t] = *reinterpret_cast<const bf16x8*>(kb + base + (size_t)((t << 4) + rlane) * 32 + (glane << 3));
    qf[t] = *reinterpret_cast<const bf16x8*>(qb + base + (size_t)((t << 4) + rlane) * 32 + (glane << 3));
  }
  if (rlane >= 1) { kf[3] = (bf16x8)0; qf[3] = (bf16x8)0; }   // rows >= 49

  f32x4 st[4][4] = {};   // [kt][qt]
#pragma unroll
  for (int kt = 0; kt < 4; ++kt)
#pragma unroll
    for (int qt = 0; qt < 4; ++qt)
      st[kt][qt] = __builtin_amdgcn_mfma_f32_16x16x32_bf16(kf[kt], qf[qt], st[kt][qt], 0, 0, 0);

  // ---- bias + softmax (per lane: 4 q's x 16 k's) ----
#pragma unroll
  for (int qt = 0; qt < 4; ++qt) {
    const int q = (qt << 4) + rlane;
    float mx = -3.0e38f;
#pragma unroll
    for (int kt = 0; kt < 4; ++kt) {
      ushort4 b4 = *reinterpret_cast<const ushort4*>(bias + q * 64 + (kt << 4) + (glane << 2));
      st[kt][qt][0] += bf2f(b4.x);
      st[kt][qt][1] += bf2f(b4.y);
      st[kt][qt][2] += bf2f(b4.z);
      st[kt][qt][3] += bf2f(b4.w);
      mx = fmaxf(mx, fmaxf(fmaxf(st[kt][qt][0], st[kt][qt][1]),
                           fmaxf(st[kt][qt][2], st[kt][qt][3])));
    }
    mx = fmaxf(mx, __shfl_xor(mx, 16));
    mx = fmaxf(mx, __shfl_xor(mx, 32));
    float sm = 0.f;
#pragma unroll
    for (int kt = 0; kt < 4; ++kt) {
      float e0 = __expf(st[kt][qt][0] - mx);
      float e1 = __expf(st[kt][qt][1] - mx);
      float e2 = __expf(st[kt][qt][2] - mx);
      float e3 = __expf(st[kt][qt][3] - mx);
      sm += (e0 + e1) + (e2 + e3);
      ushort4 h; h.x = f2bf(e0); h.y = f2bf(e1); h.z = f2bf(e2); h.w = f2bf(e3);
      *reinterpret_cast<ushort4*>(&P[(q << 6) + (((kt << 4) + (glane << 2)) ^ ((q & 7) << 3))]) = h;
    }
    sm += __shfl_xor(sm, 16);
    sm += __shfl_xor(sm, 32);
    if (glane == 0) sums[q] = 1.0f / sm;
  }

  // ---- PV: O[q][d] = P · (V^T)^T ----
  f32x4 oacc[4][2] = {};
#pragma unroll
  for (int kb2 = 0; kb2 < 2; ++kb2) {
    const int k0 = (kb2 << 5) + (glane << 3);
    bf16x8 vf[2];
#pragma unroll
    for (int nt = 0; nt < 2; ++nt) {
      int d = (nt << 4) + rlane;
      vf[nt] = *reinterpret_cast<const bf16x8*>(&VT[(d << 6) + (k0 ^ ((d & 7) << 3))]);
    }
#pragma unroll
    for (int mt = 0; mt < 4; ++mt) {
      int q2 = (mt << 4) + rlane;
      bf16x8 pf = *reinterpret_cast<const bf16x8*>(&P[(q2 << 6) + (k0 ^ ((q2 & 7) << 3))]);
#pragma unroll
      for (int nt = 0; nt < 2; ++nt)
        oacc[mt][nt] = __builtin_amdgcn_mfma_f32_16x16x32_bf16(pf, vf[nt], oacc[mt][nt], 0, 0, 0);
    }
  }

  // ---- epilogue: apply 1/sum, store q<49 ----
  u16* Ob = O + (size_t)wl * 49 * 256 + head * 32;
#pragma unroll
  for (int mt = 0; mt < 4; ++mt) {
    float4 s4 = *reinterpret_cast<const float4*>(&sums[(mt << 4) + (glane << 2)]);
    float sv[4] = {s4.x, s4.y, s4.z, s4.w};
#pragma unroll
    for (int j = 0; j < 4; ++j) {
      int q = (mt << 4) + (glane << 2) + j;
      if (q < 49) {
#pragma unroll
        for (int nt = 0; nt < 2; ++nt)
          Ob[(size_t)q * 256 + (nt << 4) + rlane] = f2bf(oacc[mt][nt][j] * sv[j]);
      }
    }
  }
}

// ---------------------------------------------------------------------------
extern "C" void kernel_launch(void* const* d_in, const int* in_sizes, int n_in,
                              void* d_out, int out_size, void* d_ws, size_t ws_size,
                              hipStream_t stream) {
  const float* x      = (const float*)d_in[0];
  const float* n1w    = (const float*)d_in[1];
  const float* n1b    = (const float*)d_in[2];
  const float* qkv_w  = (const float*)d_in[3];
  const float* qkv_b  = (const float*)d_in[4];
  const float* rpb    = (const float*)d_in[5];
  const float* proj_w = (const float*)d_in[6];
  const float* proj_b = (const float*)d_in[7];
  const float* n2w    = (const float*)d_in[8];
  const float* n2b    = (const float*)d_in[9];
  const float* fc1_w  = (const float*)d_in[10];
  const float* fc1_b  = (const float*)d_in[11];
  const float* fc2_w  = (const float*)d_in[12];
  const float* fc2_b  = (const float*)d_in[13];
  float* out = (float*)d_out;

  u16* wsu = (u16*)d_ws;
  u16* lnc = wsu;                           // CQE (per-chunk LN output)
  u16* qc = wsu + (size_t)CQE;
  u16* kc = qc + CQE;
  u16* vc = kc + CQE;
  u16* Oc = vc + CQE;
  u16* hidden = qc;                         // overlays qc..Oc (CR*1024)
  u16* wq = wsu + 5 * (size_t)CQE;
  u16* wp = wq + 196608;
  u16* w1 = wp + 65536;
  u16* w2 = w1 + 262144;
  u16* bias4 = w2 + 262144;                 // 100352 u16

  k_cvtw<<<768, 256, 0, stream>>>(qkv_w, proj_w, fc1_w, fc2_w, wq, wp, w1, w2);
  k_bias<<<32, 256, 0, stream>>>(rpb, bias4);

  for (int c = 0; c < CHUNKS; ++c) {
    k_ln<<<CR / 4, 256, 0, stream>>>(x, lnc, n1w, n1b, 1, c * CR);

    GP p1{}; p1.A = lnc; p1.B = wq; p1.bias = qkv_b;
    p1.K = 256; p1.q = qc; p1.k = kc; p1.v = vc; p1.m_base = c * CR;
    k_gemm<E_QKV><<<dim3(6, 196), 256, 0, stream>>>(p1);

    k_attn<<<CW * 8 / 4, 256, 0, stream>>>(qc, kc, vc, bias4, Oc);

    GP p2{}; p2.A = Oc; p2.B = wp; p2.bias = proj_b; p2.K = 256;
    p2.out = out; p2.resid = x; p2.m_base = c * CR;
    k_gemm<E_PROJ><<<dim3(2, 196), 256, 0, stream>>>(p2);
  }

  for (int c = 0; c < CHUNKS; ++c) {
    k_ln<<<CR / 4, 256, 0, stream>>>(out, lnc, n2w, n2b, 0, c * CR);

    GP p3{}; p3.A = lnc; p3.B = w1; p3.bias = fc1_b;
    p3.K = 256; p3.outb = hidden; p3.m_base = c * CR;
    k_gemm<E_FC1><<<dim3(8, 196), 256, 0, stream>>>(p3);

    GP p4{}; p4.A = hidden; p4.B = w2; p4.bias = fc2_b; p4.K = 1024;
    p4.out = out; p4.resid = out; p4.m_base = c * CR;
    k_gemm<E_FC2><<<dim3(2, 196), 256, 0, stream>>>(p4);
  }
}